// Round 12
// baseline (238.346 us; speedup 1.0000x reference)
//
#include <hip/hip_runtime.h>

typedef __bf16 bf16;
typedef __bf16 bf16x8 __attribute__((ext_vector_type(8)));
typedef float f32x4 __attribute__((ext_vector_type(4)));

__device__ __forceinline__ void gll16(const void* g, void* l) {
    __builtin_amdgcn_global_load_lds((const __attribute__((address_space(1))) void*)g,
                                     (__attribute__((address_space(3))) void*)l, 16, 0, 0);
}

// counted-wait + barrier in one asm (no memory op can slip between); "memory" clobber
// doubles as a compiler fence so LDS reads can't be hoisted across the wait.
#define WBAR(N) asm volatile("s_waitcnt vmcnt(" #N ")\n\ts_barrier" ::: "memory")

// gelu via sigmoid identity: 0.5(1+tanh(u)) == sigmoid(2u). 8 VALU ops, no branches.
__device__ __forceinline__ float gelu_f(float v) {
    float x2 = v * v;
    float sn = v * fmaf(-0.0713540072f, x2, -1.5957691216f);   // -2u
    float e  = __expf(sn);
    return v * __builtin_amdgcn_rcpf(1.0f + e);
}

// ---------------- prep: 4 weight transposes (blocks 0..1535) + dual LN (blocks 1536..2047) ----
__launch_bounds__(256)
__global__ void prep_kernel(const float* __restrict__ wqkv, const float* __restrict__ wout,
                            const float* __restrict__ wff1, const float* __restrict__ wff2,
                            bf16* __restrict__ wqkvT, bf16* __restrict__ woutT,
                            bf16* __restrict__ wff1T, bf16* __restrict__ wff2T,
                            const float* __restrict__ x,
                            const float* __restrict__ g1, const float* __restrict__ b1,
                            const float* __restrict__ g2, const float* __restrict__ b2,
                            bf16* __restrict__ a, bf16* __restrict__ f) {
    __shared__ __align__(16) float smem[12672 + 512 + 64];
    const int tid = threadIdx.x;
    int g = blockIdx.x;
    if (g < 1536) {
        float (*tl)[33] = (float (*)[33])smem;
        const float* in; bf16* out; int R, Cc, bx, by;
        if (g < 288)       { in = wqkv; out = wqkvT; R = 384;  Cc = 768;  bx = g % 24; by = g / 24; }
        else if (g < 384)  { g -= 288; in = wout; out = woutT; R = 256;  Cc = 384;  bx = g % 12; by = g / 12; }
        else if (g < 960)  { g -= 384; in = wff1; out = wff1T; R = 384;  Cc = 1536; bx = g % 48; by = g / 48; }
        else               { g -= 960; in = wff2; out = wff2T; R = 1536; Cc = 384;  bx = g % 12; by = g / 12; }
        const int c0 = bx * 32, r0 = by * 32;
        const int cl = tid & 31, r8 = tid >> 5;
#pragma unroll
        for (int k = 0; k < 4; k++) {
            int r = k * 8 + r8;
            tl[r][cl] = in[(size_t)(r0 + r) * Cc + c0 + cl];
        }
        __syncthreads();
#pragma unroll
        for (int k = 0; k < 4; k++) {
            int cc = k * 8 + r8;
            out[(size_t)(c0 + cc) * R + r0 + cl] = (bf16)tl[cl][cc];
        }
        return;
    }
    g -= 1536;
    float (*tile)[33] = (float (*)[33])smem;
    float (*S)[32]  = (float (*)[32])(smem + 12672);
    float (*SS)[32] = (float (*)[32])(smem + 12928);
    float* Mn = smem + 13184;
    float* Rs = smem + 13216;
    const int bb = g >> 3;
    const int i0 = (g & 7) * 32;
    {
        const int i_l = tid & 31, c_l = tid >> 5;
        const size_t base = (size_t)bb * 384 * 256 + i0 + i_l;
#pragma unroll 6
        for (int c = c_l; c < 384; c += 8)
            tile[c][i_l] = x[base + (size_t)c * 256];
    }
    __syncthreads();
    {
        const int i_s = tid & 31, p = tid >> 5;
        float s = 0.f, ss = 0.f;
#pragma unroll 6
        for (int j = 0; j < 48; j++) {
            float v = tile[p * 48 + j][i_s];
            s += v; ss += v * v;
        }
        S[p][i_s] = s; SS[p][i_s] = ss;
    }
    __syncthreads();
    if (tid < 32) {
        float t1 = 0.f, t2 = 0.f;
#pragma unroll
        for (int p = 0; p < 8; p++) { t1 += S[p][tid]; t2 += SS[p][tid]; }
        float mean = t1 * (1.0f / 384.0f);
        float var  = t2 * (1.0f / 384.0f) - mean * mean;
        Mn[tid] = mean;
        Rs[tid] = rsqrtf(var + 1e-5f);
    }
    __syncthreads();
    const int lane = tid & 63, w = tid >> 6;
#pragma unroll
    for (int rr = 0; rr < 8; rr++) {
        const int i = w * 8 + rr;
        const float mean = Mn[i], rstd = Rs[i];
        const size_t orow = ((size_t)bb * 256 + i0 + i) * 384;
#pragma unroll
        for (int pass = 0; pass < 6; pass++) {
            const int c = pass * 64 + lane;
            float nh = (tile[c][i] - mean) * rstd;
            a[orow + c] = (bf16)(nh * g1[c] + b1[c]);
            f[orow + c] = (bf16)(nh * g2[c] + b2[c]);
        }
    }
}

// ========== 256x256 GEMM: 512 thr / 8 waves, BK=32, 3-buffer depth-2 counted pipeline =======
// Halves BOTH cache-reread factors vs 128^2 (A x N/BN, B x M/BM) -- the measured ~7 TB/s
// composite L2/L3 read throughput is the wall, so traffic/2 => time/2. Wave w owns 64x128
// (wm=(w&3)*64, wn=(w>>2)*128, acc[4][8]); 32 MFMA/wave/step. 4 gll16/thread/stage; WBAR(4)
// drains only the oldest stage. LDS 3 x 32KB = 96KB -> 1 block/CU (8 waves = 2/SIMD).
// R7 swizzle carries over: all row bases are multiples of 16, so ksw/rsw formulas unchanged.
#define STAGE256(buf, kb)                                                   \
    {                                                                       \
        bf16* sA = lds + (buf) * 16384;                                     \
        bf16* sB = sA + 8192;                                               \
        gll16(Abase + (size_t)rS * K + (kb) + ksw, sA + tid * 8);           \
        gll16(Abase + (size_t)(rS + 128) * K + (kb) + ksw, sA + (tid + 512) * 8); \
        gll16(Bbase + (size_t)rS * K + (kb) + ksw, sB + tid * 8);           \
        gll16(Bbase + (size_t)(rS + 128) * K + (kb) + ksw, sB + (tid + 512) * 8); \
    }
#define COMPUTE256(buf)                                                     \
    {                                                                       \
        const bf16* sA = lds + (buf) * 16384;                               \
        const bf16* sB = sA + 8192;                                         \
        bf16x8 af[4], bfr[8];                                               \
        _Pragma("unroll") for (int i = 0; i < 4; i++)                       \
            af[i] = *(const bf16x8*)(sA + (wm + i * 16 + l16) * 32 + rsw);  \
        _Pragma("unroll") for (int j = 0; j < 8; j++)                       \
            bfr[j] = *(const bf16x8*)(sB + (wn + j * 16 + l16) * 32 + rsw); \
        _Pragma("unroll") for (int i = 0; i < 4; i++)                       \
            _Pragma("unroll") for (int j = 0; j < 8; j++)                   \
                acc[i][j] = __builtin_amdgcn_mfma_f32_16x16x32_bf16(af[i], bfr[j], acc[i][j], 0, 0, 0); \
    }

template <int EPI>
__launch_bounds__(512)
__global__ void gemm256(const bf16* __restrict__ A, const bf16* __restrict__ Bt,
                        const float* __restrict__ bias, bf16* __restrict__ C,
                        int M, int N, int K, int nx) {
    __shared__ __align__(16) bf16 lds[49152];          // 96 KB
    const int tid = threadIdx.x;
    const int g = blockIdx.x;
    const int x_ = (g >> 3) % nx;
    const int y_ = (g & 7) + 8 * (g / (8 * nx));
    const int m0 = y_ * 256, n0 = x_ * 256;
    const int lane = tid & 63, w = tid >> 6;
    const int l16 = lane & 15, quad = lane >> 4;
    const int wm = (w & 3) * 64, wn = (w >> 2) * 128;
    f32x4 acc[4][8];
    { f32x4 z = {0.f, 0.f, 0.f, 0.f};
#pragma unroll
      for (int i = 0; i < 4; i++)
#pragma unroll
          for (int j = 0; j < 8; j++) acc[i][j] = z; }
    const int rS = tid >> 2;
    const int ksw = (((tid & 3) ^ ((tid >> 3) & 3)) * 8);
    const int rsw = ((quad ^ ((l16 >> 1) & 3)) * 8);
    const bf16* Abase = A + (size_t)m0 * K;
    const bf16* Bbase = Bt + (size_t)n0 * K;

    STAGE256(0, 0);
    STAGE256(1, 32);
    const int nt = K >> 5;
    int t = 0;
    for (; t < nt - 2; ++t) {
        WBAR(4);
        STAGE256((t + 2) % 3, (t + 2) * 32);
        COMPUTE256(t % 3);
    }
    WBAR(4); COMPUTE256(t % 3); ++t;
    WBAR(0); COMPUTE256(t % 3);
    __syncthreads();

    // epilogue: two passes of 128 rows (64 KB staging each), row-major store
    const float qsc = (EPI == 3 && n0 < 256) ? 0.17677669529663687f : 1.0f;
#pragma unroll
    for (int pass = 0; pass < 2; pass++) {
        if (((w & 3) >> 1) == pass) {
            const int rbase = wm & 127;
#pragma unroll
            for (int j = 0; j < 8; j++) {
                const int col = wn + j * 16 + l16;
                float bv = 0.f;
                if (EPI == 2) bv = bias[n0 + col];
#pragma unroll
                for (int i = 0; i < 4; i++) {
                    const int row0 = rbase + i * 16 + quad * 4;
#pragma unroll
                    for (int r = 0; r < 4; r++) {
                        float v = acc[i][j][r];
                        if (EPI == 3) v *= qsc;
                        if (EPI == 2) v = gelu_f(v + bv);
                        lds[(row0 + r) * 256 + col] = (bf16)v;
                    }
                }
            }
        }
        __syncthreads();
#pragma unroll
        for (int it = 0; it < 8; it++) {
            const int ch = tid + it * 512;
            const int row = ch >> 5, cc = (ch & 31) * 8;
            *(bf16x8*)(C + (size_t)(m0 + pass * 128 + row) * N + n0 + cc) =
                *(const bf16x8*)(lds + row * 256 + cc);
        }
        __syncthreads();
    }
}

// ---------------- 128x128 compute macro (used by fin_dual) ----------------
#define COMPUTE128(buf)                                                     \
    {                                                                       \
        const bf16* sA = lds + (buf) * 8192;                                \
        const bf16* sB = sA + 4096;                                         \
        bf16x8 af[4], bfr[4];                                               \
        _Pragma("unroll") for (int i = 0; i < 4; i++)                       \
            af[i] = *(const bf16x8*)(sA + (wm + i * 16 + l16) * 32 + rsw);  \
        _Pragma("unroll") for (int j = 0; j < 4; j++)                       \
            bfr[j] = *(const bf16x8*)(sB + (wn + j * 16 + l16) * 32 + rsw); \
        _Pragma("unroll") for (int i = 0; i < 4; i++)                       \
            _Pragma("unroll") for (int j = 0; j < 4; j++)                   \
                acc[i][j] = __builtin_amdgcn_mfma_f32_16x16x32_bf16(af[i], bfr[j], acc[i][j], 0, 0, 0); \
    }

// ======== fin_dual: out[b][c][i] = x + (o@woutT + bout) + (ffh@wff2T + bff2) ========
// Chained 56-step pipeline: steps 0..47 accumulate ffh (K=1536), steps 48..55 accumulate the
// out-projection (K=256) into the SAME acc -- prefetch flows seamlessly across the transition.
__launch_bounds__(256)
__global__ void fin_dual(const bf16* __restrict__ Af, const bf16* __restrict__ Bf,
                         const bf16* __restrict__ Ao, const bf16* __restrict__ Bo,
                         const float* __restrict__ bff2, const float* __restrict__ bout,
                         const float* __restrict__ xres, float* __restrict__ out, int nx) {
    __shared__ __align__(16) bf16 lds[24576];
    const int tid = threadIdx.x;
    const int g = blockIdx.x;
    const int x_ = (g >> 3) % nx;
    const int y_ = (g & 7) + 8 * (g / (8 * nx));
    const int m0 = y_ * 128, n0 = x_ * 128;
    const int lane = tid & 63, w = tid >> 6;
    const int l16 = lane & 15, quad = lane >> 4;
    const int wm = (w & 1) * 64, wn = (w >> 1) * 64;
    f32x4 acc[4][4];
    { f32x4 z = {0.f, 0.f, 0.f, 0.f};
#pragma unroll
      for (int i = 0; i < 4; i++)
#pragma unroll
          for (int j = 0; j < 4; j++) acc[i][j] = z; }
    const int c0 = tid, c1 = tid + 256;
    const int r0 = c0 >> 2, r1 = c1 >> 2;
    const int ksw = (((tid & 3) ^ ((tid >> 3) & 3)) * 8);
    const int rsw = ((quad ^ ((l16 >> 1) & 3)) * 8);
    const bf16* A1 = Af + (size_t)m0 * 1536;
    const bf16* B1 = Bf + (size_t)n0 * 1536;
    const bf16* A2 = Ao + (size_t)m0 * 256;
    const bf16* B2 = Bo + (size_t)n0 * 256;

#define STGD(buf, s)                                                                \
    {   bf16* sA = lds + (buf) * 8192;                                              \
        bf16* sB = sA + 4096;                                                       \
        if ((s) < 48) {                                                             \
            const int kb = (s) * 32;                                                \
            gll16(A1 + (size_t)r0 * 1536 + kb + ksw, sA + c0 * 8);                  \
            gll16(A1 + (size_t)r1 * 1536 + kb + ksw, sA + c1 * 8);                  \
            gll16(B1 + (size_t)r0 * 1536 + kb + ksw, sB + c0 * 8);                  \
            gll16(B1 + (size_t)r1 * 1536 + kb + ksw, sB + c1 * 8);                  \
        } else {                                                                    \
            const int kb = ((s) - 48) * 32;                                         \
            gll16(A2 + (size_t)r0 * 256 + kb + ksw, sA + c0 * 8);                   \
            gll16(A2 + (size_t)r1 * 256 + kb + ksw, sA + c1 * 8);                   \
            gll16(B2 + (size_t)r0 * 256 + kb + ksw, sB + c0 * 8);                   \
            gll16(B2 + (size_t)r1 * 256 + kb + ksw, sB + c1 * 8);                   \
        } }

    STGD(0, 0); STGD(1, 1);
    int s = 0;
    for (; s < 54; ++s) {
        WBAR(4);
        STGD((s + 2) % 3, s + 2);
        COMPUTE128(s % 3);
    }
    WBAR(4); COMPUTE128(s % 3); ++s;
    WBAR(0); COMPUTE128(s % 3);
    __syncthreads();
#undef STGD

    // epilogue: tile[col][row] stride 132 (33 KB), then transposed f32 store + residual
#pragma unroll
    for (int j = 0; j < 4; j++) {
        const int col = wn + j * 16 + l16;
        const float bv = bff2[n0 + col] + bout[n0 + col];
#pragma unroll
        for (int i = 0; i < 4; i++) {
            const int row0 = wm + i * 16 + quad * 4;
#pragma unroll
            for (int r = 0; r < 4; r++)
                lds[col * 132 + row0 + r] = (bf16)(acc[i][j][r] + bv);
        }
    }
    __syncthreads();
    const int b = m0 >> 8, ib = m0 & 255;
#pragma unroll
    for (int it = 0; it < 8; it++) {
        const int ch = tid + it * 256;
        const int cl = ch >> 4, ic = (ch & 15) * 8;
        const size_t base = (size_t)(b * 384 + n0 + cl) * 256 + ib + ic;
        bf16x8 ff = *(const bf16x8*)(lds + cl * 132 + ic);
        const f32x4* xr = (const f32x4*)(xres + base);
        f32x4 o0, o1;
#pragma unroll
        for (int e = 0; e < 4; e++) o0[e] = xr[0][e] + (float)ff[e];
#pragma unroll
        for (int e = 0; e < 4; e++) o1[e] = xr[1][e] + (float)ff[e + 4];
        ((f32x4*)(out + base))[0] = o0;
        ((f32x4*)(out + base))[1] = o1;
    }
}

// ---------------- fused attention: one block per (b,h); qc loop inside ----------------
// Q pre-scaled by 1/sqrt(d) in the qkv epilogue; relative bias from LDS-resident sbias.
__launch_bounds__(256)
__global__ void attn_kernel(const bf16* __restrict__ qkv,
                            const float* __restrict__ btab,
                            bf16* __restrict__ o) {
    __shared__ float sbias[961];
    __shared__ __align__(16) bf16 sK[256 * 32];        // [k][d] swizzled like GEMM tiles
    __shared__ __align__(16) bf16 sVt[32][264];        // [d][k]
    __shared__ __align__(16) bf16 sP[4][16][264];
    const int tid = threadIdx.x;
    const int g = blockIdx.x;
    const int h  = (g >> 3) & 7;
    const int bb = (g & 7) + 8 * (g >> 6);
    const int lane = tid & 63, w = tid >> 6;
    const int l16 = lane & 15, quad = lane >> 4;
    const int rsw = ((quad ^ ((l16 >> 1) & 3)) * 8);
    const size_t qkvb = (size_t)bb * 256 * 768;
    const bf16* Qbase = qkv + qkvb + h * 32;
    const bf16* Kbase = qkv + qkvb + 256 + h * 32;
    const bf16* Vbase = qkv + qkvb + 512 + h * 32;

    for (int e = tid; e < 961; e += 256) sbias[e] = btab[e * 8 + h];
#pragma unroll
    for (int it = 0; it < 4; it++) {
        const int ch = it * 256 + tid;
        const int row = ch >> 2;
        const int d8 = (((ch & 3) ^ ((ch >> 3) & 3)) * 8);   // pre-swizzled source chunk
        gll16(Kbase + (size_t)row * 768 + d8, sK + ch * 8);
    }
#pragma unroll
    for (int it = 0; it < 4; it++) {
        const int ch = it * 256 + tid;
        const int k = ch >> 2, d8 = (ch & 3) * 8;
        bf16x8 vv = *(const bf16x8*)(Vbase + (size_t)k * 768 + d8);
#pragma unroll
        for (int j = 0; j < 8; j++)
            sVt[d8 + j][k] = vv[j];
    }
    __syncthreads();

    f32x4 zero = {0.f, 0.f, 0.f, 0.f};
    for (int qc = 0; qc < 4; qc++) {
        const int qbase = qc * 64 + w * 16;
        bf16x8 qf = *(const bf16x8*)(Qbase + (size_t)(qbase + l16) * 768 + quad * 8);
        f32x4 s[16];
#pragma unroll
        for (int kt = 0; kt < 16; kt++) {
            bf16x8 kf = *(const bf16x8*)(sK + (kt * 16 + l16) * 32 + rsw);
            s[kt] = __builtin_amdgcn_mfma_f32_16x16x32_bf16(qf, kf, zero, 0, 0, 0);
        }
        const int qi0 = qbase + quad * 4;
        float mx[4] = {-1e30f, -1e30f, -1e30f, -1e30f};
#pragma unroll
        for (int kt = 0; kt < 16; kt++) {
            const int j = kt * 16 + l16;
            const int yj = j >> 4, xj = j & 15;
#pragma unroll
            for (int r = 0; r < 4; r++) {
                const int q = qi0 + r;
                const int tix = ((q >> 4) - yj + 15) * 31 + ((q & 15) - xj + 15);
                float v = s[kt][r] + sbias[tix];          // q pre-scaled in qkv epilogue
                s[kt][r] = v;
                mx[r] = fmaxf(mx[r], v);
            }
        }
#pragma unroll
        for (int r = 0; r < 4; r++)
            for (int msk = 1; msk < 16; msk <<= 1)
                mx[r] = fmaxf(mx[r], __shfl_xor(mx[r], msk, 64));
        float sum[4] = {0.f, 0.f, 0.f, 0.f};
#pragma unroll
        for (int kt = 0; kt < 16; kt++)
#pragma unroll
            for (int r = 0; r < 4; r++) {
                float e = __expf(s[kt][r] - mx[r]);
                s[kt][r] = e;
                sum[r] += e;
            }
#pragma unroll
        for (int r = 0; r < 4; r++) {
            for (int msk = 1; msk < 16; msk <<= 1)
                sum[r] += __shfl_xor(sum[r], msk, 64);
            sum[r] = 1.0f / sum[r];
        }
#pragma unroll
        for (int kt = 0; kt < 16; kt++)
#pragma unroll
            for (int r = 0; r < 4; r++)
                sP[w][quad * 4 + r][kt * 16 + l16] = (bf16)(s[kt][r] * sum[r]);
        f32x4 oacc[2];
        oacc[0] = zero; oacc[1] = zero;
#pragma unroll
        for (int ks = 0; ks < 8; ks++) {
            bf16x8 pf = *(const bf16x8*)(&sP[w][l16][ks * 32 + quad * 8]);
#pragma unroll
            for (int dt = 0; dt < 2; dt++) {
                bf16x8 vf = *(const bf16x8*)(&sVt[dt * 16 + l16][ks * 32 + quad * 8]);
                oacc[dt] = __builtin_amdgcn_mfma_f32_16x16x32_bf16(pf, vf, oacc[dt], 0, 0, 0);
            }
        }
#pragma unroll
        for (int dt = 0; dt < 2; dt++)
#pragma unroll
            for (int r = 0; r < 4; r++)
                o[(size_t)(bb * 256 + qbase + quad * 4 + r) * 256 + h * 32 + dt * 16 + l16] = (bf16)oacc[dt][r];
    }
}

extern "C" void kernel_launch(void* const* d_in, const int* in_sizes, int n_in,
                              void* d_out, int out_size, void* d_ws, size_t ws_size,
                              hipStream_t stream) {
    const float* x    = (const float*)d_in[0];
    const float* g1   = (const float*)d_in[1];
    const float* b1   = (const float*)d_in[2];
    const float* wqkv = (const float*)d_in[3];
    const float* btab = (const float*)d_in[4];
    const float* wout = (const float*)d_in[5];
    const float* bout = (const float*)d_in[6];
    const float* g2   = (const float*)d_in[7];
    const float* b2   = (const float*)d_in[8];
    const float* wff1 = (const float*)d_in[9];
    const float* bff1 = (const float*)d_in[10];
    const float* wff2 = (const float*)d_in[11];
    const float* bff2 = (const float*)d_in[12];
    float* out = (float*)d_out;

    bf16* ws = (bf16*)d_ws;
    const size_t NA = 6291456;                 // 16384*384 elements
    bf16* wqkvT   = ws;                        // [768,384]
    bf16* woutT   = wqkvT + 294912;            // [384,256]
    bf16* wff1T   = woutT + 98304;             // [1536,384]
    bf16* wff2T   = wff1T + 589824;            // [384,1536]   (ends 1572864)
    bf16* f_buf   = ws + 1572864;              // [16384,384]
    bf16* a_buf   = f_buf + NA;                // [16384,384]
    bf16* qkv_buf = a_buf + NA;                // [16384,768]
    bf16* o_buf   = qkv_buf + 12582912;        // [16384,256]
    bf16* ffh_buf = o_buf + 4194304;           // [16384,1536] (ends 56098816 elem)

    dim3 b256(256);
    dim3 b512(512);
    prep_kernel<<<2048, b256, 0, stream>>>(wqkv, wout, wff1, wff2, wqkvT, woutT, wff1T, wff2T,
                                           x, g1, b1, g2, b2, a_buf, f_buf);
    // qkv projection, 256x256 tiles (q-columns pre-scaled by 1/sqrt(d)); grid 192 = 8*3*8
    gemm256<3><<<192, b512, 0, stream>>>(a_buf, wqkvT, nullptr, qkv_buf, 16384, 768, 384, 3);
    attn_kernel<<<512, b256, 0, stream>>>(qkv_buf, btab, o_buf);
    // ff1 + gelu, 256x256 tiles; grid 384 = 8*6*8
    gemm256<2><<<384, b512, 0, stream>>>(f_buf, wff1T, bff1, ffh_buf, 16384, 1536, 384, 6);
    // ff2 + out-projection + residual, dual-K accumulation
    fin_dual<<<3 * 128, b256, 0, stream>>>(ffh_buf, wff2T, o_buf, woutT, bff2, bout, x, out, 3);
}

// Round 13
// 220.121 us; speedup vs baseline: 1.0828x; 1.0828x over previous
//
#include <hip/hip_runtime.h>

typedef __bf16 bf16;
typedef __bf16 bf16x8 __attribute__((ext_vector_type(8)));
typedef float f32x4 __attribute__((ext_vector_type(4)));

__device__ __forceinline__ void gll16(const void* g, void* l) {
    __builtin_amdgcn_global_load_lds((const __attribute__((address_space(1))) void*)g,
                                     (__attribute__((address_space(3))) void*)l, 16, 0, 0);
}

// counted-wait + barrier in one asm (no memory op can slip between); "memory" clobber
// doubles as a compiler fence so LDS reads can't be hoisted across the wait.
#define WBAR(N) asm volatile("s_waitcnt vmcnt(" #N ")\n\ts_barrier" ::: "memory")

// gelu via sigmoid identity: 0.5(1+tanh(u)) == sigmoid(2u). 8 VALU ops, no branches.
__device__ __forceinline__ float gelu_f(float v) {
    float x2 = v * v;
    float sn = v * fmaf(-0.0713540072f, x2, -1.5957691216f);   // -2u
    float e  = __expf(sn);
    return v * __builtin_amdgcn_rcpf(1.0f + e);
}

// ---------------- prep: 4 weight transposes (blocks 0..1535) + dual LN (blocks 1536..2047) ----
__launch_bounds__(256)
__global__ void prep_kernel(const float* __restrict__ wqkv, const float* __restrict__ wout,
                            const float* __restrict__ wff1, const float* __restrict__ wff2,
                            bf16* __restrict__ wqkvT, bf16* __restrict__ woutT,
                            bf16* __restrict__ wff1T, bf16* __restrict__ wff2T,
                            const float* __restrict__ x,
                            const float* __restrict__ g1, const float* __restrict__ b1,
                            const float* __restrict__ g2, const float* __restrict__ b2,
                            bf16* __restrict__ a, bf16* __restrict__ f) {
    __shared__ __align__(16) float smem[12672 + 512 + 64];
    const int tid = threadIdx.x;
    int g = blockIdx.x;
    if (g < 1536) {
        float (*tl)[33] = (float (*)[33])smem;
        const float* in; bf16* out; int R, Cc, bx, by;
        if (g < 288)       { in = wqkv; out = wqkvT; R = 384;  Cc = 768;  bx = g % 24; by = g / 24; }
        else if (g < 384)  { g -= 288; in = wout; out = woutT; R = 256;  Cc = 384;  bx = g % 12; by = g / 12; }
        else if (g < 960)  { g -= 384; in = wff1; out = wff1T; R = 384;  Cc = 1536; bx = g % 48; by = g / 48; }
        else               { g -= 960; in = wff2; out = wff2T; R = 1536; Cc = 384;  bx = g % 12; by = g / 12; }
        const int c0 = bx * 32, r0 = by * 32;
        const int cl = tid & 31, r8 = tid >> 5;
#pragma unroll
        for (int k = 0; k < 4; k++) {
            int r = k * 8 + r8;
            tl[r][cl] = in[(size_t)(r0 + r) * Cc + c0 + cl];
        }
        __syncthreads();
#pragma unroll
        for (int k = 0; k < 4; k++) {
            int cc = k * 8 + r8;
            out[(size_t)(c0 + cc) * R + r0 + cl] = (bf16)tl[cl][cc];
        }
        return;
    }
    g -= 1536;
    float (*tile)[33] = (float (*)[33])smem;
    float (*S)[32]  = (float (*)[32])(smem + 12672);
    float (*SS)[32] = (float (*)[32])(smem + 12928);
    float* Mn = smem + 13184;
    float* Rs = smem + 13216;
    const int bb = g >> 3;
    const int i0 = (g & 7) * 32;
    {
        const int i_l = tid & 31, c_l = tid >> 5;
        const size_t base = (size_t)bb * 384 * 256 + i0 + i_l;
#pragma unroll 6
        for (int c = c_l; c < 384; c += 8)
            tile[c][i_l] = x[base + (size_t)c * 256];
    }
    __syncthreads();
    {
        const int i_s = tid & 31, p = tid >> 5;
        float s = 0.f, ss = 0.f;
#pragma unroll 6
        for (int j = 0; j < 48; j++) {
            float v = tile[p * 48 + j][i_s];
            s += v; ss += v * v;
        }
        S[p][i_s] = s; SS[p][i_s] = ss;
    }
    __syncthreads();
    if (tid < 32) {
        float t1 = 0.f, t2 = 0.f;
#pragma unroll
        for (int p = 0; p < 8; p++) { t1 += S[p][tid]; t2 += SS[p][tid]; }
        float mean = t1 * (1.0f / 384.0f);
        float var  = t2 * (1.0f / 384.0f) - mean * mean;
        Mn[tid] = mean;
        Rs[tid] = rsqrtf(var + 1e-5f);
    }
    __syncthreads();
    const int lane = tid & 63, w = tid >> 6;
#pragma unroll
    for (int rr = 0; rr < 8; rr++) {
        const int i = w * 8 + rr;
        const float mean = Mn[i], rstd = Rs[i];
        const size_t orow = ((size_t)bb * 256 + i0 + i) * 384;
#pragma unroll
        for (int pass = 0; pass < 6; pass++) {
            const int c = pass * 64 + lane;
            float nh = (tile[c][i] - mean) * rstd;
            a[orow + c] = (bf16)(nh * g1[c] + b1[c]);
            f[orow + c] = (bf16)(nh * g2[c] + b2[c]);
        }
    }
}

// ---------------- shared 128x128 BK=32 core: 3-buffer depth-2 counted-vmcnt pipeline ---------
// (R7 swizzled LDS layout: chunk' = chunk ^ ((row>>1)&3), pre-swizzled on the gll16 SOURCE.)
#define STAGE128(buf, kb)                                                   \
    {                                                                       \
        bf16* sA = lds + (buf) * 8192;                                      \
        bf16* sB = sA + 4096;                                               \
        gll16(Abase + (size_t)r0 * K + (kb) + ksw, sA + c0 * 8);            \
        gll16(Abase + (size_t)r1 * K + (kb) + ksw, sA + c1 * 8);            \
        gll16(Bbase + (size_t)r0 * K + (kb) + ksw, sB + c0 * 8);            \
        gll16(Bbase + (size_t)r1 * K + (kb) + ksw, sB + c1 * 8);            \
    }
#define COMPUTE128(buf)                                                     \
    {                                                                       \
        const bf16* sA = lds + (buf) * 8192;                                \
        const bf16* sB = sA + 4096;                                         \
        bf16x8 af[4], bfr[4];                                               \
        _Pragma("unroll") for (int i = 0; i < 4; i++)                       \
            af[i] = *(const bf16x8*)(sA + (wm + i * 16 + l16) * 32 + rsw);  \
        _Pragma("unroll") for (int j = 0; j < 4; j++)                       \
            bfr[j] = *(const bf16x8*)(sB + (wn + j * 16 + l16) * 32 + rsw); \
        _Pragma("unroll") for (int i = 0; i < 4; i++)                       \
            _Pragma("unroll") for (int j = 0; j < 4; j++)                   \
                acc[i][j] = __builtin_amdgcn_mfma_f32_16x16x32_bf16(af[i], bfr[j], acc[i][j], 0, 0, 0); \
    }
#define GEMM128_PRO_KLOOP(BID)                                                       \
    const int x_ = ((BID) >> 3) % nx;                                                \
    const int y_ = ((BID) & 7) + 8 * ((BID) / (8 * nx));                             \
    const int m0 = y_ * 128, n0 = x_ * 128;                                          \
    const int lane = tid & 63, w = tid >> 6;                                         \
    const int l16 = lane & 15, quad = lane >> 4;                                     \
    const int wm = (w & 1) * 64, wn = (w >> 1) * 64;                                 \
    f32x4 zero = {0.f, 0.f, 0.f, 0.f};                                               \
    f32x4 acc[4][4];                                                                 \
    _Pragma("unroll") for (int i = 0; i < 4; i++)                                    \
        _Pragma("unroll") for (int j = 0; j < 4; j++) acc[i][j] = zero;              \
    const int c0 = tid, c1 = tid + 256;                                              \
    const int r0 = c0 >> 2, r1 = c1 >> 2;                                            \
    const int ksw = (((tid & 3) ^ ((tid >> 3) & 3)) * 8);                            \
    const int rsw = ((quad ^ ((l16 >> 1) & 3)) * 8);                                 \
    const bf16* Abase = A + (size_t)m0 * K;                                          \
    const bf16* Bbase = Bt + (size_t)n0 * K;                                         \
    STAGE128(0, 0);                                                                  \
    STAGE128(1, 32);                                                                 \
    const int nt = K >> 5;                                                           \
    int t = 0;                                                                       \
    for (; t < nt - 2; ++t) {                                                        \
        WBAR(4);                                                                     \
        STAGE128((t + 2) % 3, (t + 2) * 32);                                         \
        COMPUTE128(t % 3);                                                           \
    }                                                                                \
    WBAR(4); COMPUTE128(t % 3); ++t;                                                 \
    WBAR(0); COMPUTE128(t % 3);                                                      \
    __syncthreads();

// ---- GEMM 128x128 row-major epilogue. EPI: 0=plain, 2=bias+gelu, 3=scale q-cols (qkv) ----
template <int EPI>
__launch_bounds__(256)
__global__ void gemm_bt(const bf16* __restrict__ A, const bf16* __restrict__ Bt,
                        const float* __restrict__ bias, bf16* __restrict__ C,
                        int M, int N, int K, int nx) {
    __shared__ __align__(16) bf16 lds[24576];
    const int tid = threadIdx.x;
    GEMM128_PRO_KLOOP(blockIdx.x)
    const float qsc = (EPI == 3 && n0 < 256) ? 0.17677669529663687f : 1.0f;
#pragma unroll
    for (int j = 0; j < 4; j++) {
        const int col = wn + j * 16 + l16;
        float bv = 0.f;
        if (EPI == 2) bv = bias[n0 + col];
#pragma unroll
        for (int i = 0; i < 4; i++) {
            const int row0 = wm + i * 16 + quad * 4;
#pragma unroll
            for (int r = 0; r < 4; r++) {
                float v = acc[i][j][r];
                if (EPI == 3) v *= qsc;
                if (EPI == 2) v = gelu_f(v + bv);
                lds[(row0 + r) * 128 + col] = (bf16)v;
            }
        }
    }
    __syncthreads();
#pragma unroll
    for (int it = 0; it < 8; it++) {
        const int ch = tid + it * 256;
        const int row = ch >> 4, cc = (ch & 15) * 8;
        *(bf16x8*)(C + (size_t)(m0 + row) * N + n0 + cc) = *(const bf16x8*)(lds + row * 128 + cc);
    }
}

// ======== fin_dual: out[b][c][i] = x + (o@woutT + bout) + (ffh@wff2T + bff2) ========
// Chained 56-step pipeline: steps 0..47 accumulate ffh (K=1536), steps 48..55 accumulate the
// out-projection (K=256) into the SAME acc -- prefetch flows seamlessly across the transition.
__launch_bounds__(256)
__global__ void fin_dual(const bf16* __restrict__ Af, const bf16* __restrict__ Bf,
                         const bf16* __restrict__ Ao, const bf16* __restrict__ Bo,
                         const float* __restrict__ bff2, const float* __restrict__ bout,
                         const float* __restrict__ xres, float* __restrict__ out, int nx) {
    __shared__ __align__(16) bf16 lds[24576];
    const int tid = threadIdx.x;
    const int g = blockIdx.x;
    const int x_ = (g >> 3) % nx;
    const int y_ = (g & 7) + 8 * (g / (8 * nx));
    const int m0 = y_ * 128, n0 = x_ * 128;
    const int lane = tid & 63, w = tid >> 6;
    const int l16 = lane & 15, quad = lane >> 4;
    const int wm = (w & 1) * 64, wn = (w >> 1) * 64;
    f32x4 acc[4][4];
    { f32x4 z = {0.f, 0.f, 0.f, 0.f};
#pragma unroll
      for (int i = 0; i < 4; i++)
#pragma unroll
          for (int j = 0; j < 4; j++) acc[i][j] = z; }
    const int c0 = tid, c1 = tid + 256;
    const int r0 = c0 >> 2, r1 = c1 >> 2;
    const int ksw = (((tid & 3) ^ ((tid >> 3) & 3)) * 8);
    const int rsw = ((quad ^ ((l16 >> 1) & 3)) * 8);
    const bf16* A1 = Af + (size_t)m0 * 1536;
    const bf16* B1 = Bf + (size_t)n0 * 1536;
    const bf16* A2 = Ao + (size_t)m0 * 256;
    const bf16* B2 = Bo + (size_t)n0 * 256;

#define STGD(buf, s)                                                                \
    {   bf16* sA = lds + (buf) * 8192;                                              \
        bf16* sB = sA + 4096;                                                       \
        if ((s) < 48) {                                                             \
            const int kb = (s) * 32;                                                \
            gll16(A1 + (size_t)r0 * 1536 + kb + ksw, sA + c0 * 8);                  \
            gll16(A1 + (size_t)r1 * 1536 + kb + ksw, sA + c1 * 8);                  \
            gll16(B1 + (size_t)r0 * 1536 + kb + ksw, sB + c0 * 8);                  \
            gll16(B1 + (size_t)r1 * 1536 + kb + ksw, sB + c1 * 8);                  \
        } else {                                                                    \
            const int kb = ((s) - 48) * 32;                                         \
            gll16(A2 + (size_t)r0 * 256 + kb + ksw, sA + c0 * 8);                   \
            gll16(A2 + (size_t)r1 * 256 + kb + ksw, sA + c1 * 8);                   \
            gll16(B2 + (size_t)r0 * 256 + kb + ksw, sB + c0 * 8);                   \
            gll16(B2 + (size_t)r1 * 256 + kb + ksw, sB + c1 * 8);                   \
        } }

    STGD(0, 0); STGD(1, 1);
    int s = 0;
    for (; s < 54; ++s) {
        WBAR(4);
        STGD((s + 2) % 3, s + 2);
        COMPUTE128(s % 3);
    }
    WBAR(4); COMPUTE128(s % 3); ++s;
    WBAR(0); COMPUTE128(s % 3);
    __syncthreads();
#undef STGD

    // epilogue: tile[col][row] stride 132 (33 KB), then transposed f32 store + residual
#pragma unroll
    for (int j = 0; j < 4; j++) {
        const int col = wn + j * 16 + l16;
        const float bv = bff2[n0 + col] + bout[n0 + col];
#pragma unroll
        for (int i = 0; i < 4; i++) {
            const int row0 = wm + i * 16 + quad * 4;
#pragma unroll
            for (int r = 0; r < 4; r++)
                lds[col * 132 + row0 + r] = (bf16)(acc[i][j][r] + bv);
        }
    }
    __syncthreads();
    const int b = m0 >> 8, ib = m0 & 255;
#pragma unroll
    for (int it = 0; it < 8; it++) {
        const int ch = tid + it * 256;
        const int cl = ch >> 4, ic = (ch & 15) * 8;
        const size_t base = (size_t)(b * 384 + n0 + cl) * 256 + ib + ic;
        bf16x8 ff = *(const bf16x8*)(lds + cl * 132 + ic);
        const f32x4* xr = (const f32x4*)(xres + base);
        f32x4 o0, o1;
#pragma unroll
        for (int e = 0; e < 4; e++) o0[e] = xr[0][e] + (float)ff[e];
#pragma unroll
        for (int e = 0; e < 4; e++) o1[e] = xr[1][e] + (float)ff[e + 4];
        ((f32x4*)(out + base))[0] = o0;
        ((f32x4*)(out + base))[1] = o1;
    }
}

// ---------------- fused attention: one block per (b,h); qc loop inside ----------------
// Q pre-scaled by 1/sqrt(d) in the qkv epilogue; relative bias from LDS-resident sbias.
__launch_bounds__(256)
__global__ void attn_kernel(const bf16* __restrict__ qkv,
                            const float* __restrict__ btab,
                            bf16* __restrict__ o) {
    __shared__ float sbias[961];
    __shared__ __align__(16) bf16 sK[256 * 32];        // [k][d] swizzled like GEMM tiles
    __shared__ __align__(16) bf16 sVt[32][264];        // [d][k]
    __shared__ __align__(16) bf16 sP[4][16][264];
    const int tid = threadIdx.x;
    const int g = blockIdx.x;
    const int h  = (g >> 3) & 7;
    const int bb = (g & 7) + 8 * (g >> 6);
    const int lane = tid & 63, w = tid >> 6;
    const int l16 = lane & 15, quad = lane >> 4;
    const int rsw = ((quad ^ ((l16 >> 1) & 3)) * 8);
    const size_t qkvb = (size_t)bb * 256 * 768;
    const bf16* Qbase = qkv + qkvb + h * 32;
    const bf16* Kbase = qkv + qkvb + 256 + h * 32;
    const bf16* Vbase = qkv + qkvb + 512 + h * 32;

    for (int e = tid; e < 961; e += 256) sbias[e] = btab[e * 8 + h];
#pragma unroll
    for (int it = 0; it < 4; it++) {
        const int ch = it * 256 + tid;
        const int row = ch >> 2;
        const int d8 = (((ch & 3) ^ ((ch >> 3) & 3)) * 8);   // pre-swizzled source chunk
        gll16(Kbase + (size_t)row * 768 + d8, sK + ch * 8);
    }
#pragma unroll
    for (int it = 0; it < 4; it++) {
        const int ch = it * 256 + tid;
        const int k = ch >> 2, d8 = (ch & 3) * 8;
        bf16x8 vv = *(const bf16x8*)(Vbase + (size_t)k * 768 + d8);
#pragma unroll
        for (int j = 0; j < 8; j++)
            sVt[d8 + j][k] = vv[j];
    }
    __syncthreads();

    f32x4 zero = {0.f, 0.f, 0.f, 0.f};
    for (int qc = 0; qc < 4; qc++) {
        const int qbase = qc * 64 + w * 16;
        bf16x8 qf = *(const bf16x8*)(Qbase + (size_t)(qbase + l16) * 768 + quad * 8);
        f32x4 s[16];
#pragma unroll
        for (int kt = 0; kt < 16; kt++) {
            bf16x8 kf = *(const bf16x8*)(sK + (kt * 16 + l16) * 32 + rsw);
            s[kt] = __builtin_amdgcn_mfma_f32_16x16x32_bf16(qf, kf, zero, 0, 0, 0);
        }
        const int qi0 = qbase + quad * 4;
        float mx[4] = {-1e30f, -1e30f, -1e30f, -1e30f};
#pragma unroll
        for (int kt = 0; kt < 16; kt++) {
            const int j = kt * 16 + l16;
            const int yj = j >> 4, xj = j & 15;
#pragma unroll
            for (int r = 0; r < 4; r++) {
                const int q = qi0 + r;
                const int tix = ((q >> 4) - yj + 15) * 31 + ((q & 15) - xj + 15);
                float v = s[kt][r] + sbias[tix];          // q pre-scaled in qkv epilogue
                s[kt][r] = v;
                mx[r] = fmaxf(mx[r], v);
            }
        }
#pragma unroll
        for (int r = 0; r < 4; r++)
            for (int msk = 1; msk < 16; msk <<= 1)
                mx[r] = fmaxf(mx[r], __shfl_xor(mx[r], msk, 64));
        float sum[4] = {0.f, 0.f, 0.f, 0.f};
#pragma unroll
        for (int kt = 0; kt < 16; kt++)
#pragma unroll
            for (int r = 0; r < 4; r++) {
                float e = __expf(s[kt][r] - mx[r]);
                s[kt][r] = e;
                sum[r] += e;
            }
#pragma unroll
        for (int r = 0; r < 4; r++) {
            for (int msk = 1; msk < 16; msk <<= 1)
                sum[r] += __shfl_xor(sum[r], msk, 64);
            sum[r] = 1.0f / sum[r];
        }
#pragma unroll
        for (int kt = 0; kt < 16; kt++)
#pragma unroll
            for (int r = 0; r < 4; r++)
                sP[w][quad * 4 + r][kt * 16 + l16] = (bf16)(s[kt][r] * sum[r]);
        f32x4 oacc[2];
        oacc[0] = zero; oacc[1] = zero;
#pragma unroll
        for (int ks = 0; ks < 8; ks++) {
            bf16x8 pf = *(const bf16x8*)(&sP[w][l16][ks * 32 + quad * 8]);
#pragma unroll
            for (int dt = 0; dt < 2; dt++) {
                bf16x8 vf = *(const bf16x8*)(&sVt[dt * 16 + l16][ks * 32 + quad * 8]);
                oacc[dt] = __builtin_amdgcn_mfma_f32_16x16x32_bf16(pf, vf, oacc[dt], 0, 0, 0);
            }
        }
#pragma unroll
        for (int dt = 0; dt < 2; dt++)
#pragma unroll
            for (int r = 0; r < 4; r++)
                o[(size_t)(bb * 256 + qbase + quad * 4 + r) * 256 + h * 32 + dt * 16 + l16] = (bf16)oacc[dt][r];
    }
}

extern "C" void kernel_launch(void* const* d_in, const int* in_sizes, int n_in,
                              void* d_out, int out_size, void* d_ws, size_t ws_size,
                              hipStream_t stream) {
    const float* x    = (const float*)d_in[0];
    const float* g1   = (const float*)d_in[1];
    const float* b1   = (const float*)d_in[2];
    const float* wqkv = (const float*)d_in[3];
    const float* btab = (const float*)d_in[4];
    const float* wout = (const float*)d_in[5];
    const float* bout = (const float*)d_in[6];
    const float* g2   = (const float*)d_in[7];
    const float* b2   = (const float*)d_in[8];
    const float* wff1 = (const float*)d_in[9];
    const float* bff1 = (const float*)d_in[10];
    const float* wff2 = (const float*)d_in[11];
    const float* bff2 = (const float*)d_in[12];
    float* out = (float*)d_out;

    bf16* ws = (bf16*)d_ws;
    const size_t NA = 6291456;                 // 16384*384 elements
    bf16* wqkvT   = ws;                        // [768,384]
    bf16* woutT   = wqkvT + 294912;            // [384,256]
    bf16* wff1T   = woutT + 98304;             // [1536,384]
    bf16* wff2T   = wff1T + 589824;            // [384,1536]   (ends 1572864)
    bf16* f_buf   = ws + 1572864;              // [16384,384]
    bf16* a_buf   = f_buf + NA;                // [16384,384]
    bf16* qkv_buf = a_buf + NA;                // [16384,768]
    bf16* o_buf   = qkv_buf + 12582912;        // [16384,256]
    bf16* ffh_buf = o_buf + 4194304;           // [16384,1536] (ends 56098816 elem)

    dim3 b256(256);
    prep_kernel<<<2048, b256, 0, stream>>>(wqkv, wout, wff1, wff2, wqkvT, woutT, wff1T, wff2T,
                                           x, g1, b1, g2, b2, a_buf, f_buf);
    // qkv projection (q-columns pre-scaled by 1/sqrt(d))
    gemm_bt<3><<<6 * 128, b256, 0, stream>>>(a_buf, wqkvT, nullptr, qkv_buf, 16384, 768, 384, 6);
    attn_kernel<<<512, b256, 0, stream>>>(qkv_buf, btab, o_buf);
    // ff1 + gelu
    gemm_bt<2><<<12 * 128, b256, 0, stream>>>(f_buf, wff1T, bff1, ffh_buf, 16384, 1536, 384, 12);
    // ff2 + out-projection + residual, dual-K accumulation
    fin_dual<<<3 * 128, b256, 0, stream>>>(ffh_buf, wff2T, o_buf, woutT, bff2, bout, x, out, 3);
}